// Round 11
// baseline (2985.358 us; speedup 1.0000x reference)
//
#include <hip/hip_runtime.h>

static constexpr int   BATCH = 131072;
static constexpr int   TS    = 30;
static constexpr int   DD    = 10;
static constexpr int   HH    = 20;
static constexpr float EPSV  = 1e-5f;
static constexpr float INV_B = 1.0f / (float)BATCH;

static constexpr int NBLK = 256;   // cooperative: 1 block/CU guaranteed
static constexpr int NTHR = 512;   // 1 row/thread
static constexpr int NS   = 4;     // stat slot spread (blockIdx&3)
static constexpr int NVA  = 230;   // 210 tri second-moments + 20 sums
static constexpr int NVB  = 40;    // 20 sums + 20 sumsq
static constexpr int STRA = NVA * NS;   // 920 floats / t
static constexpr int STRB = NVB * NS;   // 160 floats / t
static constexpr int CTRW = 16;         // one 64B-padded counter per step

__device__ __forceinline__ int tri(int k, int l) {  // k <= l
    return k * (41 - k) / 2 + (l - k);
}

template <int CTRL>
__device__ __forceinline__ float dpp_add(float v) {
    int x = __builtin_amdgcn_update_dpp(0, __float_as_int(v), CTRL, 0xF, 0xF, true);
    return v + __int_as_float(x);
}

__device__ __forceinline__ float rowsum16(float v) {
    v = dpp_add<0x111>(v);
    v = dpp_add<0x112>(v);
    v = dpp_add<0x114>(v);
    v = dpp_add<0x118>(v);
    return v;   // lane 15 of each 16 holds the total
}

__device__ __forceinline__ float aloadf(const float* p) {
    return __hip_atomic_load(p, __ATOMIC_RELAXED, __HIP_MEMORY_SCOPE_AGENT);
}

// R1's exact proven barrier: release arrival, acquire spin, flat counter.
__device__ __forceinline__ void gbar(unsigned* __restrict__ c, int tid) {
    __syncthreads();   // drains this block's vmem (incl. stat atomics)
    if (tid == 0) {
        __hip_atomic_fetch_add(c, 1u, __ATOMIC_RELEASE, __HIP_MEMORY_SCOPE_AGENT);
        while (__hip_atomic_load(c, __ATOMIC_ACQUIRE, __HIP_MEMORY_SCOPE_AGENT) < (unsigned)NBLK)
            __builtin_amdgcn_s_sleep(1);
    }
    __syncthreads();
}

// ---------------- init: prev=0, statsA(0) ----------------
__global__ void __launch_bounds__(NTHR)
k_init(const float* __restrict__ x, float* __restrict__ prevg, float* __restrict__ redA)
{
    __shared__ float lred[32 * NVA];
    const int tid     = threadIdx.x;
    const int grp     = tid >> 4;
    const bool lane15 = (tid & 15) == 15;
    const int row     = blockIdx.x * NTHR + tid;

    float xv[DD];
    {
        const float2* px = reinterpret_cast<const float2*>(x + (size_t)row * TS * DD);
#pragma unroll
        for (int i = 0; i < 5; ++i) { float2 v = px[i]; xv[2 * i] = v.x; xv[2 * i + 1] = v.y; }
    }
#pragma unroll
    for (int d = 0; d < DD; ++d) prevg[(size_t)d * BATCH + row] = 0.0f;

#define H0(i) ((i) < DD ? xv[i] : 0.0f)
    {
        int v = 0;
#pragma unroll
        for (int k = 0; k < 2 * DD; ++k) {
#pragma unroll
            for (int l = k; l < 2 * DD; ++l) {
                float r = rowsum16(H0(k) * H0(l));
                if (lane15) lred[grp * NVA + v] = r;
                ++v;
            }
        }
#pragma unroll
        for (int k = 0; k < 2 * DD; ++k) {
            float r = rowsum16(H0(k));
            if (lane15) lred[grp * NVA + 210 + k] = r;
        }
    }
#undef H0
    __syncthreads();
    if (tid < NVA) {
        float acc = 0.0f;
#pragma unroll
        for (int g = 0; g < 32; ++g) acc += lred[g * NVA + tid];
        atomicAdd(redA + tid * NS + (blockIdx.x & (NS - 1)), acc);
    }
}

// ---------------- one full step: paramsA + fwd + statsB | gbar | paramsB + out + statsA(t+1)
template <bool LAST>
__global__ void __launch_bounds__(NTHR, 1)
k_step(const float* __restrict__ x, float* __restrict__ prevg, float* __restrict__ outg,
       const float* __restrict__ W1, const float* __restrict__ W2,
       const float* __restrict__ W3, const float* __restrict__ b3,
       const float* __restrict__ g0, const float* __restrict__ be0,
       const float* __restrict__ g1, const float* __restrict__ be1,
       const float* __restrict__ g2, const float* __restrict__ be2,
       float* __restrict__ redA, float* __restrict__ redB,
       unsigned* __restrict__ ctr, int t)
{
    __shared__ float lred[32 * NVA];
    __shared__ float sM[230], sMu[20], sCov[400], sU[400], sP[400];
    __shared__ float sW1[400], sW2[400], sW3[200], sB3[10];
    __shared__ float sA0[20], sC0[20], sA1[20], sC1[20], sA2[20], sC2[20];

    const int tid     = threadIdx.x;
    const int grp     = tid >> 4;
    const bool lane15 = (tid & 15) == 15;
    const int slot    = blockIdx.x & (NS - 1);
    const int row     = blockIdx.x * NTHR + tid;

    // ---- hoisted per-row loads (latency overlaps the param preamble)
    float xv[DD], pv[DD], xn[DD];
    {
        const float2* px = reinterpret_cast<const float2*>(x + (size_t)row * TS * DD + t * DD);
#pragma unroll
        for (int i = 0; i < 5; ++i) { float2 v = px[i]; xv[2 * i] = v.x; xv[2 * i + 1] = v.y; }
    }
#pragma unroll
    for (int d = 0; d < DD; ++d) pv[d] = prevg[(size_t)d * BATCH + row];
    if constexpr (!LAST) {
        const float2* px = reinterpret_cast<const float2*>(x + (size_t)row * TS * DD + (t + 1) * DD);
#pragma unroll
        for (int i = 0; i < 5; ++i) { float2 v = px[i]; xn[2 * i] = v.x; xn[2 * i + 1] = v.y; }
    }

    // ---- stage weights
    if (tid < 400) { sW1[tid] = W1[t * 400 + tid]; sW2[tid] = W2[t * 400 + tid]; }
    if (tid < 200) sW3[tid] = W3[t * 200 + tid];
    if (tid >= 500 && tid < 510) sB3[tid - 500] = b3[t * DD + (tid - 500)];

    // ---- readback statsA (written by previous kernel; relaxed agent loads)
    if (tid < NVA) {
        const float* p = redA + (size_t)t * STRA + tid * NS;
        float s = 0.0f;
#pragma unroll
        for (int i = 0; i < NS; ++i) s += aloadf(p + i);
        sM[tid] = s;
    }
    __syncthreads();

    // ---- BN0 params
    if (tid < 20) {
        float mu  = sM[210 + tid] * INV_B;
        float var = fmaf(-mu, mu, sM[tri(tid, tid)] * INV_B);
        float a   = g0[t * 20 + tid] * rsqrtf(var + EPSV);
        sA0[tid] = a;
        sC0[tid] = fmaf(-mu, a, be0[t * 20 + tid]);
        sMu[tid] = mu;
    }
    __syncthreads();

    // ---- covariance + U = W1 ∘ A0
    if (tid < 400) {
        int k = tid / 20, l = tid % 20;
        int a = k < l ? k : l, b = k < l ? l : k;
        sCov[tid] = fmaf(-sMu[k], sMu[l], sM[tri(a, b)] * INV_B);
        sU[tid]   = sW1[tid] * sA0[l];
    }
    __syncthreads();

    // ---- P[j,k] = U[j,k] * (Cov[k,:] · U[j,:])
    if (tid < 400) {
        int j = tid / 20, k = tid % 20;
        float acc = 0.0f;
#pragma unroll
        for (int l = 0; l < 20; ++l)
            acc = fmaf(sCov[k * 20 + l], sU[j * 20 + l], acc);
        sP[tid] = acc * sU[tid];
    }
    __syncthreads();

    // ---- analytic BN1 params (b1 cancels in BN)
    if (tid < 20) {
        float var1 = 0.0f, m1 = 0.0f;
#pragma unroll
        for (int k = 0; k < 20; ++k) {
            var1 += sP[tid * 20 + k];
            m1    = fmaf(sU[tid * 20 + k], sMu[k], m1);
            m1    = fmaf(sW1[tid * 20 + k], sC0[k], m1);
        }
        float a1 = g1[t * 20 + tid] * rsqrtf(var1 + EPSV);
        sA1[tid] = a1;
        sC1[tid] = fmaf(-m1, a1, be1[t * 20 + tid]);
    }
    __syncthreads();

    // ---- forward layers 1,2 (y2 stays in registers across the barrier)
    float hn[20];
#pragma unroll
    for (int k = 0; k < 10; ++k) hn[k]      = fmaf(xv[k], sA0[k],      sC0[k]);
#pragma unroll
    for (int k = 0; k < 10; ++k) hn[10 + k] = fmaf(pv[k], sA0[10 + k], sC0[10 + k]);

    float h1[20];
#pragma unroll
    for (int j = 0; j < 20; ++j) {
        float y = 0.0f;
#pragma unroll
        for (int k = 0; k < 20; ++k) y = fmaf(sW1[j * 20 + k], hn[k], y);
        h1[j] = fmaxf(fmaf(y, sA1[j], sC1[j]), 0.0f);
    }
    float y2[20];
#pragma unroll
    for (int j = 0; j < 20; ++j) {
        float y = 0.0f;
#pragma unroll
        for (int k = 0; k < 20; ++k) y = fmaf(sW2[j * 20 + k], h1[k], y);
        y2[j] = y;   // b2 cancels in BN2
    }

    // ---- statsB
#pragma unroll
    for (int j = 0; j < 20; ++j) {
        float r = rowsum16(y2[j]);
        if (lane15) lred[grp * NVB + j] = r;
    }
#pragma unroll
    for (int j = 0; j < 20; ++j) {
        float r = rowsum16(y2[j] * y2[j]);
        if (lane15) lred[grp * NVB + 20 + j] = r;
    }
    __syncthreads();
    if (tid < NVB) {
        float acc = 0.0f;
#pragma unroll
        for (int g = 0; g < 32; ++g) acc += lred[g * NVB + tid];
        atomicAdd(redB + (size_t)t * STRB + tid * NS + slot, acc);
    }

    // ================= grid barrier =================
    gbar(ctr + (size_t)t * CTRW, tid);

    // ---- BN2 params
    if (tid < NVB) {
        const float* p = redB + (size_t)t * STRB + tid * NS;
        float s = 0.0f;
#pragma unroll
        for (int i = 0; i < NS; ++i) s += aloadf(p + i);
        sM[tid] = s;
    }
    __syncthreads();
    if (tid < 20) {
        float m   = sM[tid] * INV_B;
        float var = fmaf(-m, m, sM[20 + tid] * INV_B);
        float a   = g2[t * 20 + tid] * rsqrtf(var + EPSV);
        sA2[tid] = a;
        sC2[tid] = fmaf(-m, a, be2[t * 20 + tid]);
    }
    __syncthreads();

    // ---- layer 3 + output + prev
    float h2[20];
#pragma unroll
    for (int j = 0; j < 20; ++j)
        h2[j] = fmaxf(fmaf(y2[j], sA2[j], sC2[j]), 0.0f);

    float ov[DD];
#pragma unroll
    for (int d = 0; d < DD; ++d) {
        float a = sB3[d];
#pragma unroll
        for (int j = 0; j < 20; ++j)
            a = fmaf(sW3[d * 20 + j], h2[j], a);
        ov[d] = a;
    }
    {
        float2* po = reinterpret_cast<float2*>(outg + (size_t)row * TS * DD + t * DD);
#pragma unroll
        for (int i = 0; i < 5; ++i) po[i] = make_float2(ov[2 * i], ov[2 * i + 1]);
    }
#pragma unroll
    for (int d = 0; d < DD; ++d) prevg[(size_t)d * BATCH + row] = ov[d];

    // ---- statsA(t+1) (kernel boundary is the sync for these)
    if constexpr (!LAST) {
#define H0(i) ((i) < DD ? xn[i] : ov[(i) - DD])
        {
            int v = 0;
#pragma unroll
            for (int k = 0; k < 2 * DD; ++k) {
#pragma unroll
                for (int l = k; l < 2 * DD; ++l) {
                    float r = rowsum16(H0(k) * H0(l));
                    if (lane15) lred[grp * NVA + v] = r;
                    ++v;
                }
            }
#pragma unroll
            for (int k = 0; k < 2 * DD; ++k) {
                float r = rowsum16(H0(k));
                if (lane15) lred[grp * NVA + 210 + k] = r;
            }
        }
#undef H0
        __syncthreads();
        if (tid < NVA) {
            float acc = 0.0f;
#pragma unroll
            for (int g = 0; g < 32; ++g) acc += lred[g * NVA + tid];
            atomicAdd(redA + (size_t)(t + 1) * STRA + tid * NS + slot, acc);
        }
    }
}

extern "C" void kernel_launch(void* const* d_in, const int* in_sizes, int n_in,
                              void* d_out, int out_size, void* d_ws, size_t ws_size,
                              hipStream_t stream) {
    const float* x   = (const float*)d_in[0];
    const float* g0  = (const float*)d_in[1];
    const float* be0 = (const float*)d_in[2];
    const float* W1  = (const float*)d_in[3];
    const float* b1  = (const float*)d_in[4];   (void)b1;  // cancels in BN1
    const float* g1  = (const float*)d_in[5];
    const float* be1 = (const float*)d_in[6];
    const float* W2  = (const float*)d_in[7];
    const float* b2  = (const float*)d_in[8];   (void)b2;  // cancels in BN2
    const float* g2  = (const float*)d_in[9];
    const float* be2 = (const float*)d_in[10];
    const float* W3  = (const float*)d_in[11];
    const float* b3  = (const float*)d_in[12];
    float* out = (float*)d_out;

    const size_t redA_f = (size_t)TS * STRA;    // 27600
    const size_t redB_f = (size_t)TS * STRB;    //  4800
    const size_t ctr_u  = (size_t)TS * CTRW;    //   480
    float*    redA  = (float*)d_ws;
    float*    redB  = redA + redA_f;
    unsigned* ctr   = (unsigned*)(redB + redB_f);
    float*    prevg = (float*)(ctr + ctr_u);    // [DD][BATCH] 5.2 MB (fully written by k_init)

    // zero stat accumulators + barrier counters each replay
    hipMemsetAsync(d_ws, 0, (redA_f + redB_f) * 4 + ctr_u * 4, stream);

    k_init<<<BATCH / NTHR, NTHR, 0, stream>>>(x, prevg, redA);

    for (int t = 0; t < TS; ++t) {
        void* args[] = { (void*)&x, (void*)&prevg, (void*)&out,
                         (void*)&W1, (void*)&W2, (void*)&W3, (void*)&b3,
                         (void*)&g0, (void*)&be0, (void*)&g1, (void*)&be1,
                         (void*)&g2, (void*)&be2,
                         (void*)&redA, (void*)&redB, (void*)&ctr, (void*)&t };
        if (t + 1 < TS)
            hipLaunchCooperativeKernel((const void*)k_step<false>, dim3(NBLK), dim3(NTHR),
                                       args, 0, stream);
        else
            hipLaunchCooperativeKernel((const void*)k_step<true>, dim3(NBLK), dim3(NTHR),
                                       args, 0, stream);
    }
}